// Round 2
// baseline (512.376 us; speedup 1.0000x reference)
//
#include <hip/hip_runtime.h>
#include <stdint.h>

#define D      2048
#define NE     64
#define TOPK   8
#define NTOK   16384
#define KS     4            // K split factor
#define KCH    (D / KS)     // 512 k per chunk
#define PROBS_OFF 0
#define IDX_OFF   131072
#define BIAS_OFF  262144
#define EMA_OFF   262208

// d_ws layout (floats):
//   [0..63]        gcnt (as unsigned)
//   [1024..]       wT[2048][64]           (512 KB)
//   [132096..]     partial[KS*64][16384]  (16.78 MB)
#define WT_OFF   1024
#define PART_OFF 132096

// ---- transpose gw[64][2048] -> wT[2048][64] --------------------------------
__global__ __launch_bounds__(256) void wtrans(const float* __restrict__ gw,
                                              float* __restrict__ wT) {
  __shared__ float t64[NE][65];
  const int k0 = blockIdx.x * 64;
  const int tid = threadIdx.x;
#pragma unroll
  for (int r = 0; r < 16; ++r) {
    int idx = r * 256 + tid;
    int e = idx >> 6, kk = idx & 63;
    t64[e][kk] = gw[(size_t)e * D + k0 + kk];
  }
  __syncthreads();
#pragma unroll
  for (int r = 0; r < 16; ++r) {
    int idx = r * 256 + tid;
    int kk = idx >> 6, e = idx & 63;
    wT[(size_t)(k0 + kk) * NE + e] = t64[e][kk];
  }
}

// ---- phase A: logits partials. lane=token, 16 experts/wave, K split 4 ------
__global__ __launch_bounds__(256) void router_gemm(
    const float* __restrict__ x, const float* __restrict__ wT,
    float* __restrict__ partial) {
  const int tid  = threadIdx.x;
  const int wave = tid >> 6;
  const int lane = tid & 63;
  const int e0   = wave * 16;
  const int kc   = blockIdx.y;
  const int tok  = blockIdx.x * 64 + lane;
  const int kb   = kc * KCH;

  const float* xp = x + (size_t)tok * D + kb;

  float acc[16];
#pragma unroll
  for (int j = 0; j < 16; ++j) acc[j] = 0.0f;

#pragma unroll 2
  for (int k4 = 0; k4 < KCH / 4; ++k4) {
    float4 xv = *(const float4*)(xp + k4 * 4);
#pragma unroll
    for (int i = 0; i < 4; ++i) {
      const float* wr = wT + (size_t)(kb + k4 * 4 + i) * NE + e0;
      float4 wa = *(const float4*)(wr);
      float4 wb = *(const float4*)(wr + 4);
      float4 wc = *(const float4*)(wr + 8);
      float4 wd = *(const float4*)(wr + 12);
      float xk = (i == 0) ? xv.x : (i == 1) ? xv.y : (i == 2) ? xv.z : xv.w;
      acc[0]  = fmaf(xk, wa.x, acc[0]);
      acc[1]  = fmaf(xk, wa.y, acc[1]);
      acc[2]  = fmaf(xk, wa.z, acc[2]);
      acc[3]  = fmaf(xk, wa.w, acc[3]);
      acc[4]  = fmaf(xk, wb.x, acc[4]);
      acc[5]  = fmaf(xk, wb.y, acc[5]);
      acc[6]  = fmaf(xk, wb.z, acc[6]);
      acc[7]  = fmaf(xk, wb.w, acc[7]);
      acc[8]  = fmaf(xk, wc.x, acc[8]);
      acc[9]  = fmaf(xk, wc.y, acc[9]);
      acc[10] = fmaf(xk, wc.z, acc[10]);
      acc[11] = fmaf(xk, wc.w, acc[11]);
      acc[12] = fmaf(xk, wd.x, acc[12]);
      acc[13] = fmaf(xk, wd.y, acc[13]);
      acc[14] = fmaf(xk, wd.z, acc[14]);
      acc[15] = fmaf(xk, wd.w, acc[15]);
    }
  }

  // coalesced partial stores: partial[(kc*64 + e)][tok]
#pragma unroll
  for (int j = 0; j < 16; ++j)
    partial[(size_t)(kc * NE + e0 + j) * NTOK + tok] = acc[j];
}

// ---- phase B: reduce + bias + top-8 + softmax + histogram ------------------
__global__ __launch_bounds__(128) void router_topk(
    const float* __restrict__ partial, const float* __restrict__ bias,
    float* __restrict__ out, unsigned* __restrict__ gcnt) {
  __shared__ unsigned cntL[NE];
  const int tid = threadIdx.x;
  const int t   = blockIdx.x * 128 + tid;
  if (tid < NE) cntL[tid] = 0;
  __syncthreads();

  float v[NE];
#pragma unroll
  for (int e = 0; e < NE; ++e) v[e] = bias[e];
#pragma unroll
  for (int p = 0; p < KS; ++p)
#pragma unroll
    for (int e = 0; e < NE; ++e)
      v[e] += partial[(size_t)(p * NE + e) * NTOK + t];

  unsigned long long used = 0;
  float bv[TOPK];
  int   bi[TOPK];
#pragma unroll
  for (int p = 0; p < TOPK; ++p) {
    float m = -__builtin_inff();
    int mi = 0;
#pragma unroll
    for (int e = 0; e < NE; ++e) {
      bool ok = (((used >> e) & 1ull) == 0ull) && (v[e] > m);
      m  = ok ? v[e] : m;
      mi = ok ? e : mi;
    }
    used |= (1ull << mi);
    bv[p] = m;
    bi[p] = mi;
  }

  float pex[TOPK];
  float s = 0.0f;
#pragma unroll
  for (int p = 0; p < TOPK; ++p) { pex[p] = expf(bv[p] - bv[0]); s += pex[p]; }
  float inv = 1.0f / s;

  float4 o0 = make_float4(pex[0] * inv, pex[1] * inv, pex[2] * inv, pex[3] * inv);
  float4 o1 = make_float4(pex[4] * inv, pex[5] * inv, pex[6] * inv, pex[7] * inv);
  *(float4*)(out + PROBS_OFF + (size_t)t * 8)     = o0;
  *(float4*)(out + PROBS_OFF + (size_t)t * 8 + 4) = o1;
  float4 i0 = make_float4((float)bi[0], (float)bi[1], (float)bi[2], (float)bi[3]);
  float4 i1 = make_float4((float)bi[4], (float)bi[5], (float)bi[6], (float)bi[7]);
  *(float4*)(out + IDX_OFF + (size_t)t * 8)     = i0;
  *(float4*)(out + IDX_OFF + (size_t)t * 8 + 4) = i1;

#pragma unroll
  for (int p = 0; p < TOPK; ++p) atomicAdd(&cntL[bi[p]], 1u);
  __syncthreads();
  if (tid < NE) atomicAdd(&gcnt[tid], cntL[tid]);
}

// ---- finalize: EMA + bias update -------------------------------------------
__global__ __launch_bounds__(64) void router_finalize(
    const unsigned* __restrict__ gcnt, const float* __restrict__ bias,
    const float* __restrict__ ema, float* __restrict__ out) {
  int e = threadIdx.x;
  float load = (float)gcnt[e] * (1.0f / (float)NTOK);
  float ne = ema[e] * 0.95f + load * 0.05f;
  float nb = bias[e] + 0.01f * (1.0f / 64.0f - ne);
  out[BIAS_OFF + e] = nb;
  out[EMA_OFF + e]  = ne;
}

extern "C" void kernel_launch(void* const* d_in, const int* in_sizes, int n_in,
                              void* d_out, int out_size, void* d_ws, size_t ws_size,
                              hipStream_t stream) {
  const float* x    = (const float*)d_in[0];
  const float* gw   = (const float*)d_in[1];
  const float* bias = (const float*)d_in[2];
  const float* ema  = (const float*)d_in[3];
  float* out = (float*)d_out;
  float* wsf = (float*)d_ws;
  unsigned* gcnt = (unsigned*)d_ws;
  float* wT      = wsf + WT_OFF;
  float* partial = wsf + PART_OFF;

  hipMemsetAsync(d_ws, 0, NE * sizeof(unsigned), stream);
  wtrans<<<dim3(D / 64), dim3(256), 0, stream>>>(gw, wT);
  router_gemm<<<dim3(NTOK / 64, KS), dim3(256), 0, stream>>>(x, wT, partial);
  router_topk<<<dim3(NTOK / 128), dim3(128), 0, stream>>>(partial, bias, out, gcnt);
  router_finalize<<<dim3(1), dim3(64), 0, stream>>>(gcnt, bias, ema, out);
}